// Round 8
// baseline (60.409 us; speedup 1.0000x reference)
//
#include <hip/hip_runtime.h>

#define NBATCH 4096
#define NSAMP  7
#define DIM    512
#define NCB    16   // 4096 / 256 column tiles

typedef float floatx4 __attribute__((ext_vector_type(4)));
typedef short short8  __attribute__((ext_vector_type(8)));

__device__ static __forceinline__ void load16_lds(const void* g, void* l) {
  __builtin_amdgcn_global_load_lds(
      (const __attribute__((address_space(1))) unsigned int*)g,
      (__attribute__((address_space(3))) unsigned int*)l, 16, 0, 0);
}

__device__ static __forceinline__ unsigned int f2bf_rne(float f) {
  union { float f; unsigned int u; } v; v.f = f;
  unsigned int u = v.u;
  u += 0x7FFFu + ((u >> 16) & 1u);
  return u >> 16;
}

// ---------------- preprocess: out[i,d] = mean_norm[i,d] + esum[i,d]*exp(ls[i,d])/7 ----
// One WAVE per row. R8 probe: eps (112 MB of 144 MB traffic) read via
// global_load_lds DMA (no VGPR writeback path); mean/ls via VGPR float4 loads.
// Tests whether the ~12.4 GB/s/CU read rate (== m13 copy's read component) is a
// VGPR-return-path artifact or a fabric-level per-direction cap.
__global__ __launch_bounds__(256, 2) void prep_kernel(
    const float* __restrict__ qm, const float* __restrict__ qls, const float* __restrict__ eq,
    const float* __restrict__ tm, const float* __restrict__ tls, const float* __restrict__ ek,
    unsigned short* __restrict__ outA, unsigned short* __restrict__ outB,
    unsigned int* __restrict__ ticket)
{
  __shared__ char seps[4][14336];   // 56 KB: per-wave eps row staging

  const int wv   = threadIdx.x >> 6;
  const int lane = threadIdx.x & 63;
  const int gid  = blockIdx.x * 4 + wv;   // 0..8191
  const int side = gid >> 12;             // 0: query, 1: target
  const int row  = gid & (NBATCH - 1);

  if (blockIdx.x == 0 && threadIdx.x == 0) *ticket = 0;  // for fused finalize

  const float* mean = side ? tm  : qm;
  const float* ls   = side ? tls : qls;
  const float* eps  = side ? ek  : eq;
  unsigned short* out = side ? outB : outA;

  const float4* mean4 = (const float4*)(mean + (size_t)row * DIM);
  const float4* ls4   = (const float4*)(ls   + (size_t)row * DIM);
  // per-lane global source for DMA chunks (dest adds lane*16 in HW)
  const char* epsb = (const char*)(eps + (size_t)row * (NSAMP * DIM)) + lane * 16;
  char* ldst = &seps[wv][0];

  // VGPR-path loads (mean/ls) + 14 DMA chunks (eps row, 14336 B)
  const float4 m0 = mean4[lane];
  const float4 m1 = mean4[64 + lane];
  const float4 l0 = ls4[lane];
  const float4 l1 = ls4[64 + lane];
  #pragma unroll
  for (int c = 0; c < 14; ++c)
    load16_lds(epsb + c * 1024, ldst + c * 1024);

  // norm + exp on the VGPR-path data while DMAs fly
  float ss = m0.x * m0.x + m0.y * m0.y + m0.z * m0.z + m0.w * m0.w
           + m1.x * m1.x + m1.y * m1.y + m1.z * m1.z + m1.w * m1.w;
  #pragma unroll
  for (int off = 1; off < 64; off <<= 1) ss += __shfl_xor(ss, off);
  const float rnorm = 1.0f / fmaxf(sqrtf(ss), 1e-12f);
  const float inv = 1.0f / (float)NSAMP;
  const float e00 = __expf(l0.x) * inv, e01 = __expf(l0.y) * inv;
  const float e02 = __expf(l0.z) * inv, e03 = __expf(l0.w) * inv;
  const float e10 = __expf(l1.x) * inv, e11 = __expf(l1.y) * inv;
  const float e12 = __expf(l1.z) * inv, e13 = __expf(l1.w) * inv;

  // drain DMAs, then sum staged eps from LDS (conflict-free: 16 B/lane)
  asm volatile("s_waitcnt vmcnt(0)" ::: "memory");
  floatx4 a0 = (floatx4){0.f, 0.f, 0.f, 0.f};
  floatx4 a1 = (floatx4){0.f, 0.f, 0.f, 0.f};
  #pragma unroll
  for (int n = 0; n < NSAMP; ++n) {
    a0 += *(const floatx4*)(ldst + (2 * n + 0) * 1024 + lane * 16);
    a1 += *(const floatx4*)(ldst + (2 * n + 1) * 1024 + lane * 16);
  }

  const float v00 = m0.x * rnorm + a0[0] * e00;
  const float v01 = m0.y * rnorm + a0[1] * e01;
  const float v02 = m0.z * rnorm + a0[2] * e02;
  const float v03 = m0.w * rnorm + a0[3] * e03;
  const float v10 = m1.x * rnorm + a1[0] * e10;
  const float v11 = m1.y * rnorm + a1[1] * e11;
  const float v12 = m1.z * rnorm + a1[2] * e12;
  const float v13 = m1.w * rnorm + a1[3] * e13;

  unsigned int* o32 = (unsigned int*)(out + (size_t)row * DIM);
  uint2 p0, p1;
  p0.x = f2bf_rne(v00) | (f2bf_rne(v01) << 16);
  p0.y = f2bf_rne(v02) | (f2bf_rne(v03) << 16);
  p1.x = f2bf_rne(v10) | (f2bf_rne(v11) << 16);
  p1.y = f2bf_rne(v12) | (f2bf_rne(v13) << 16);
  ((uint2*)o32)[lane] = p0;
  ((uint2*)(o32 + 128))[lane] = p1;
}

// ---------------- fused 256x256 GEMM + per-block LSE partials ----------------
// S = A*B^T, A,B [4096,512] bf16 K-contiguous. 256^2 tile, 8 waves (2Mx4N),
// BK=64, double-buffered LDS (128 KB), phase-split K-loop, XOR-swizzled LDS
// (byte ^= (row&7)<<4; pre-swizzled global source, rule #21 both-sides).

__device__ static __forceinline__ void stage_half(
    const unsigned short* __restrict__ Abf, const unsigned short* __restrict__ Bbf,
    int tileRow, int tileCol, int h, int kt, char* ldsbuf, int tid)
{
  const char* gsrc;
  if (h < 2) gsrc = (const char*)Abf + ((size_t)(tileRow * 256 + h * 128)) * (DIM * 2) + (size_t)kt * 128;
  else       gsrc = (const char*)Bbf + ((size_t)(tileCol * 256 + (h - 2) * 128)) * (DIM * 2) + (size_t)kt * 128;
  char* ldst = ldsbuf + h * 16384;
  #pragma unroll
  for (int q = 0; q < 2; ++q) {
    const int slot = q * 512 + tid;
    const int r    = slot >> 3;
    const int sc   = (slot & 7) ^ (r & 7);           // inverse-swizzled source chunk
    load16_lds(gsrc + (size_t)r * (DIM * 2) + sc * 16, ldst + slot * 16);
  }
}

__device__ static __forceinline__ short8 lds_frag(const char* base, int R, int c16) {
  return *(const short8*)(base + R * 128 + (((c16 ^ (R & 7)) << 4)));
}

__global__ __launch_bounds__(512) void gemm_lse_kernel(
    const unsigned short* __restrict__ Abf, const unsigned short* __restrict__ Bbf,
    float2* __restrict__ partial, float* __restrict__ diag)
{
  extern __shared__ char lds[];   // 131072 B, passed at launch

  const int tid  = threadIdx.x;
  const int lane = tid & 63;
  const int wv   = tid >> 6;     // 0..7
  const int wm   = wv >> 2;      // 0..1  (M half)
  const int wn   = wv & 3;       // 0..3  (N quarter)
  const int fr   = lane & 15;
  const int kg   = lane >> 4;

  const int tileRow = blockIdx.y;
  const int tileCol = blockIdx.x;

  floatx4 acc[8][4];
  #pragma unroll
  for (int m = 0; m < 8; ++m)
    #pragma unroll
    for (int n = 0; n < 4; ++n)
      acc[m][n] = (floatx4){0.f, 0.f, 0.f, 0.f};

  // prologue: stage K-tile 0 into buffer 0
  #pragma unroll
  for (int h = 0; h < 4; ++h)
    stage_half(Abf, Bbf, tileRow, tileCol, h, 0, lds, tid);
  __syncthreads();   // vmcnt(0) drain -> tile 0 ready

  short8 bb[4][2];
  for (int t = 0; t < 8; ++t) {
    const int ct = t & 1;
    const char* bA = lds + ct * 65536;
    const char* bB = bA + 32768;
    char* nbuf = lds + (ct ^ 1) * 65536;

    #pragma unroll
    for (int p = 0; p < 4; ++p) {
      // stage one half-tile of K-tile t+1 (stays in flight across phases)
      if (t < 7) stage_half(Abf, Bbf, tileRow, tileCol, p, t + 1, nbuf, tid);

      // A fragments for this phase's two M-rows (both 32-K steps)
      const short8 a00 = lds_frag(bA, wm * 128 + (2 * p + 0) * 16 + fr, kg);
      const short8 a01 = lds_frag(bA, wm * 128 + (2 * p + 0) * 16 + fr, 4 + kg);
      const short8 a10 = lds_frag(bA, wm * 128 + (2 * p + 1) * 16 + fr, kg);
      const short8 a11 = lds_frag(bA, wm * 128 + (2 * p + 1) * 16 + fr, 4 + kg);
      if (p == 0) {
        #pragma unroll
        for (int n = 0; n < 4; ++n) {
          bb[n][0] = lds_frag(bB, wn * 64 + n * 16 + fr, kg);
          bb[n][1] = lds_frag(bB, wn * 64 + n * 16 + fr, 4 + kg);
        }
      }

      __builtin_amdgcn_s_barrier();
      __builtin_amdgcn_s_setprio(1);
      #pragma unroll
      for (int n = 0; n < 4; ++n) {
        acc[2 * p + 0][n] = __builtin_amdgcn_mfma_f32_16x16x32_bf16(a00, bb[n][0], acc[2 * p + 0][n], 0, 0, 0);
        acc[2 * p + 0][n] = __builtin_amdgcn_mfma_f32_16x16x32_bf16(a01, bb[n][1], acc[2 * p + 0][n], 0, 0, 0);
        acc[2 * p + 1][n] = __builtin_amdgcn_mfma_f32_16x16x32_bf16(a10, bb[n][0], acc[2 * p + 1][n], 0, 0, 0);
        acc[2 * p + 1][n] = __builtin_amdgcn_mfma_f32_16x16x32_bf16(a11, bb[n][1], acc[2 * p + 1][n], 0, 0, 0);
      }
      __builtin_amdgcn_s_setprio(0);
      __builtin_amdgcn_s_barrier();
    }
    __syncthreads();  // drain: next tile's staged halves landed
  }

  // epilogue: per-row (max,sum) over this wave's 64 cols -> LDS merge over 4 wn.
  float2* part = (float2*)lds;   // 256 rows x 4 wn (K-loop done, buffers dead)
  #pragma unroll
  for (int m = 0; m < 8; ++m) {
    #pragma unroll
    for (int rr = 0; rr < 4; ++rr) {
      const int lrow = wm * 128 + m * 16 + kg * 4 + rr;
      const int gi = tileRow * 256 + lrow;
      float lm = -3.0e38f;
      #pragma unroll
      for (int n = 0; n < 4; ++n) {
        const float c = acc[m][n][rr];
        const int gj = tileCol * 256 + wn * 64 + n * 16 + fr;
        if (gi == gj) diag[gi] = c;   // exact f32 S[i,i]
        lm = fmaxf(lm, c);
      }
      #pragma unroll
      for (int off = 1; off < 16; off <<= 1) lm = fmaxf(lm, __shfl_xor(lm, off));
      float s = 0.f;
      #pragma unroll
      for (int n = 0; n < 4; ++n) s += __expf(acc[m][n][rr] - lm);
      #pragma unroll
      for (int off = 1; off < 16; off <<= 1) s += __shfl_xor(s, off);
      if (fr == 0) part[lrow * 4 + wn] = make_float2(lm, s);
    }
  }
  __syncthreads();
  if (tid < 256) {
    float2 p0 = part[tid * 4 + 0], p1 = part[tid * 4 + 1];
    float2 p2 = part[tid * 4 + 2], p3 = part[tid * 4 + 3];
    float M = fmaxf(fmaxf(p0.x, p1.x), fmaxf(p2.x, p3.x));
    float S = p0.y * __expf(p0.x - M) + p1.y * __expf(p1.x - M)
            + p2.y * __expf(p2.x - M) + p3.y * __expf(p3.x - M);
    partial[(size_t)(tileRow * 256 + tid) * NCB + tileCol] = make_float2(M, S);
  }
}

// ---------------- finalize: per-row LSE merge; last block sums & writes loss ----
__global__ __launch_bounds__(256) void finalize_kernel(
    const float2* __restrict__ partial, const float* __restrict__ diag,
    float* __restrict__ blocksum, unsigned int* __restrict__ ticket,
    float* __restrict__ out)
{
  const int i = blockIdx.x * 256 + threadIdx.x;  // row
  const float2* p = partial + (size_t)i * NCB;
  float M = -3.0e38f;
  #pragma unroll
  for (int k = 0; k < NCB; ++k) M = fmaxf(M, p[k].x);
  float S = 0.f;
  #pragma unroll
  for (int k = 0; k < NCB; ++k) S += p[k].y * __expf(p[k].x - M);
  float v = M + logf(S) - diag[i];

  #pragma unroll
  for (int off = 1; off < 64; off <<= 1) v += __shfl_xor(v, off);
  __shared__ float wss[4];
  __shared__ bool isLast;
  if ((threadIdx.x & 63) == 0) wss[threadIdx.x >> 6] = v;
  __syncthreads();
  if (threadIdx.x == 0) {
    blocksum[blockIdx.x] = wss[0] + wss[1] + wss[2] + wss[3];
    __threadfence();
    isLast = (atomicAdd(ticket, 1u) == 15u);
  }
  __syncthreads();
  if (isLast && threadIdx.x == 0) {
    __threadfence();
    float s = 0.f;
    #pragma unroll
    for (int k = 0; k < 16; ++k) s += ((volatile float*)blocksum)[k];
    out[0] = s * (1.0f / (float)NBATCH);
  }
}

extern "C" void kernel_launch(void* const* d_in, const int* in_sizes, int n_in,
                              void* d_out, int out_size, void* d_ws, size_t ws_size,
                              hipStream_t stream) {
  const float* qm  = (const float*)d_in[0];
  const float* qls = (const float*)d_in[1];
  const float* tm  = (const float*)d_in[2];
  const float* tls = (const float*)d_in[3];
  const float* eq  = (const float*)d_in[4];
  const float* ek  = (const float*)d_in[5];
  float* out = (float*)d_out;

  char* ws = (char*)d_ws;
  unsigned short* Abf = (unsigned short*)ws;                          // 4 MB
  unsigned short* Bbf = (unsigned short*)(ws + (size_t)4194304);      // 4 MB
  float2* partial = (float2*)(ws + (size_t)8388608);                  // 512 KB (4096 x 16)
  float*  diag    = (float*)(ws + (size_t)8388608 + 524288);          // 16 KB
  float*  blocksum= (float*)(ws + (size_t)8388608 + 524288 + 16384);  // 64 B
  unsigned int* ticket = (unsigned int*)(ws + (size_t)8388608 + 524288 + 16384 + 64);

  prep_kernel<<<dim3(NBATCH * 2 / 4), 256, 0, stream>>>(qm, qls, eq, tm, tls, ek, Abf, Bbf, ticket);
  gemm_lse_kernel<<<dim3(NCB, NCB), 512, 131072, stream>>>(Abf, Bbf, partial, diag);
  finalize_kernel<<<NBATCH / 256, 256, 0, stream>>>(partial, diag, blocksum, ticket, out);
}